// Round 7
// baseline (17.342 us; speedup 1.0000x reference)
//
#include <hip/hip_runtime.h>
#include <math.h>

// feat: (N=4, C3=147, H=64, W=64) fp32 ; out: (4, 3, 256, 256) fp32
// Exact structure (proved in fp32, incl. the 1e-6 shift and clipping):
//  - interior j-group q (lane jg=q>=1): iw-minus = q-1, iw-plus = q for ALL
//    4 j's of the group; lane 0 (merged {0,1,254,255}): pair0 -> col 0 both,
//    pair1 -> col 63 both.  Same structure on the i axis per block.
//  - rel_plus = rel_minus - 2 (interior) or rel_minus (boundary) exactly ->
//    embed(rel-2) = sign-flip of embed(rel) on components {1,2,5,6}.
// XCD partitioning: bid%8 -> XCD (measured round-robin). Decode gives each
// XCD one n and a contiguous 32-wide ib range -> per-XCD working set
// 147ch x 33rows x 64cols x 4B ~= 1.24 MB < 4 MB L2 -> no HBM re-fetch.

#define FH 64
#define FW 64
#define NC3 147
#define OHW 256
#define CPAD 52          // 49 ch padded to 13 float4; 2-way-at-worst banks (free)
#define LDSZ (2 * FW * CPAD)   // 26624 B

__device__ __forceinline__ void embed7(float r, float e[7]) {
    const float F1  = 1.5707963705062866f;  // float32(0.5*pi)
    const float SQ2 = 1.4142135381698608f;  // float32(sqrt(2))
    float a = r * F1;
    float s1 = __sinf(a), c1 = __cosf(a);
    float s2 = 2.0f * s1 * c1, c2 = c1 * c1 - s1 * s1;
    float s3 = s2 * c1 + c2 * s1, c3 = c2 * c1 - s2 * s1;
    e[0] = 1.0f;
    e[1] = SQ2 * c1; e[2] = SQ2 * s1;
    e[3] = SQ2 * c2; e[4] = SQ2 * s2;
    e[5] = SQ2 * c3; e[6] = SQ2 * s3;
}

// block = (k, ib, n) via XCD-bijective decode; wave = i-member m; lane = j-group jg.
__global__ __launch_bounds__(256, 3) void ope_render_kernel(
    const float* __restrict__ feat,
    const int* __restrict__ pflip1,
    const int* __restrict__ pflip3,
    float* __restrict__ out)
{
    __shared__ float lds[LDSZ];   // [rowHalf(2)][col(64)][CPAD]

    const int tid = threadIdx.x;
    // XCD-aware decode: xcd = bid&7 owns pairs [32*xcd, 32*xcd+32)
    const int bid = blockIdx.x;        // 0..767
    const int xcd = bid & 7;
    const int rr  = bid >> 3;          // 0..95
    const int pl  = rr / 3;            // 0..31
    const int k   = rr - 3 * pl;       // 0..2
    const int pair = (xcd << 5) + pl;  // 0..255
    const int n   = pair >> 6;         // 0..3
    const int ib  = pair & 63;         // 0..63 (ib==0 merged {0,1,254,255})
    const int flip1 = pflip1[0];
    const int flip3 = pflip3[0];

    const bool boundary = (ib == 0);
    const int rA = boundary ? 0  : (ib - 1);
    const int rB = boundary ? 63 : ib;

    // ---- async-stage: issue all global loads first ----
    float4 sv[7];
    {
        const int cbase = k * 49;
        #pragma unroll
        for (int it = 0; it < 7; ++it) {
            int u = tid + it * 256;                 // u = (g*2 + d)*64 + col
            if (u < 2 * 13 * FW) {
                int col = u & 63;
                int d   = (u >> 6) & 1;
                int g   = u >> 7;                   // 0..12
                int row = d ? rB : rA;
                const float* __restrict__ src =
                    feat + (((size_t)n * NC3 + cbase + 4 * g) * FH + row) * FW + col;
                float4 v;
                v.x = src[0];
                v.y = (4 * g + 1 < 49) ? src[FH * FW]     : 0.0f;
                v.z = (4 * g + 2 < 49) ? src[2 * FH * FW] : 0.0f;
                v.w = (4 * g + 3 < 49) ? src[3 * FH * FW] : 0.0f;
                sv[it] = v;
            }
        }
    }

    // ---- short x-axis math overlaps load latency ----
    const int m  = tid >> 6;      // wave id = i-member
    const int jg = tid & 63;      // lane = j-group
    const bool fx = (flip1 == 2) || (flip1 == 4);
    const bool fy = (flip1 == 1) || (flip1 == 4);
    const bool o  = (jg == 0);
    const float sgx = (flip3 == 2 || flip3 == 4) ? -1.0f : 1.0f;
    const float sgy = (flip3 == 1 || flip3 == 4) ? -1.0f : 1.0f;

    const int i_e = boundary ? ((m < 2) ? m : 252 + m) : (4 * ib - 2 + m);
    const float cx = -1.0f + (2.0f * (float)i_e + 1.0f) * (1.0f / 256.0f);
    const int d0 = boundary ? (m >> 1) : 0;      // LDS row-half, minus corner
    const int d1 = boundary ? d0       : 1;      // plus corner
    const int row0 = d0 ? rB : rA;
    const float qh0 = -1.0f + (2.0f * (float)row0 + 1.0f) * (1.0f / 64.0f);
    const float rel0_0 = (cx - qh0) * 64.0f;                  // exact
    const float rel0_1 = boundary ? rel0_0 : (rel0_0 - 2.0f); // exact

    float ex0[7], ex1[7];
    embed7(sgx * rel0_0, ex0);
    {   // embed(r-2) = sign-flip on {1,2,5,6}; boundary: identical
        const float xm = boundary ? 1.0f : -1.0f;
        ex1[0] = 1.0f;
        ex1[1] = xm * ex0[1]; ex1[2] = xm * ex0[2];
        ex1[3] = ex0[3];      ex1[4] = ex0[4];
        ex1[5] = xm * ex0[5]; ex1[6] = xm * ex0[6];
    }

    // ---- write staged data ASAP, barrier ----
    {
        #pragma unroll
        for (int it = 0; it < 7; ++it) {
            int u = tid + it * 256;
            if (u < 2 * 13 * FW) {
                int col = u & 63;
                int d   = (u >> 6) & 1;
                int g   = u >> 7;
                *(float4*)&lds[(size_t)((d << 6) + col) * CPAD + 4 * g] = sv[it];
            }
        }
    }
    __syncthreads();

    // ---- streamed contraction (ds_reads issue first; y-math below hides them)
    float cv0[7], cv1[7];
    #pragma unroll
    for (int b = 0; b < 7; ++b) { cv0[b] = 0.0f; cv1[b] = 0.0f; }
    {
        const float4* __restrict__ bp0 =
            (const float4*)&lds[(size_t)((d0 << 6) + jg) * CPAD];
        #pragma unroll
        for (int g = 0; g < 13; ++g) {
            float4 v = bp0[g];
            float ve[4] = { v.x, v.y, v.z, v.w };
            #pragma unroll
            for (int e = 0; e < 4; ++e) {
                int ch = 4 * g + e;                    // folds to constant
                if (ch < 49) cv0[ch % 7] = fmaf(ex0[ch / 7], ve[e], cv0[ch % 7]);
            }
        }
        if (!boundary) {
            const float4* __restrict__ bp1 =
                (const float4*)&lds[(size_t)((d1 << 6) + jg) * CPAD];
            #pragma unroll
            for (int g = 0; g < 13; ++g) {
                float4 v = bp1[g];
                float ve[4] = { v.x, v.y, v.z, v.w };
                #pragma unroll
                for (int e = 0; e < 4; ++e) {
                    int ch = 4 * g + e;
                    if (ch < 49) cv1[ch % 7] = fmaf(ex1[ch / 7], ve[e], cv1[ch % 7]);
                }
            }
        } else {
            #pragma unroll
            for (int b = 0; b < 7; ++b) cv1[b] = cv0[b];  // same row, same ex
        }
    }

    // ---- y-axis embeds + weights (post-barrier: overlaps ds_read latency) ----
    const float tm = o ? 0.0f : -2.0f;   // rel1_plus = rel1_minus + tm
    const float ym = o ? 1.0f : -1.0f;   // ey1 sign multiplier
    float eyv[2][2][7];
    float wts[2][2][4];
    #pragma unroll
    for (int p = 0; p < 2; ++p) {
        const int jb = o ? (p ? 254 : 0) : (4 * jg - 2 + 2 * p);
        const int cm = o ? (p ? 63 : 0) : (jg - 1);      // minus-corner col
        const float qwm = -1.0f + (2.0f * (float)cm + 1.0f) * (1.0f / 64.0f);
        #pragma unroll
        for (int sub = 0; sub < 2; ++sub) {
            const int j_e = jb + sub;
            const float cy = -1.0f + (2.0f * (float)j_e + 1.0f) * (1.0f / 256.0f);
            const float rel1m = (cy - qwm) * 64.0f;      // exact
            const float rel1p = rel1m + tm;              // exact

            float a00 = fabsf(rel0_0 * rel1m) + 1e-9f;
            float a01 = fabsf(rel0_0 * rel1p) + 1e-9f;
            float a10 = fabsf(rel0_1 * rel1m) + 1e-9f;
            float a11 = fabsf(rel0_1 * rel1p) + 1e-9f;
            float tot = ((a00 + a01) + a10) + a11;
            float rinv = __builtin_amdgcn_rcpf(tot);
            wts[p][sub][0] = a11 * rinv;   // w00
            wts[p][sub][1] = a10 * rinv;   // w01
            wts[p][sub][2] = a01 * rinv;   // w10
            wts[p][sub][3] = a00 * rinv;   // w11

            embed7(sgy * rel1m, eyv[p][sub]);
        }
    }

    // ---- neighbor column via shuffle (lane jg-1; lane0 <- lane63) ----
    const int srcl = (jg + 63) & 63;
    float qv0[7], qv1[7];
    #pragma unroll
    for (int b = 0; b < 7; ++b) {
        qv0[b] = __shfl(cv0[b], srcl, 64);
        qv1[b] = __shfl(cv1[b], srcl, 64);
    }

    // ---- dots; colvec choice is static for interior lanes ----
    float acc0, acc1, acc2, acc3;
    #pragma unroll
    for (int p = 0; p < 2; ++p) {
        // minus-corner colvec A, plus-corner colvec B (per dx):
        // p0: A = o?cv:qv, B = cv ;  p1: A = qv, B = o?qv:cv
        float A0[7], A1[7], B0[7], B1[7];
        #pragma unroll
        for (int b = 0; b < 7; ++b) {
            if (p == 0) {
                A0[b] = o ? cv0[b] : qv0[b];
                A1[b] = o ? cv1[b] : qv1[b];
                B0[b] = cv0[b];
                B1[b] = cv1[b];
            } else {
                A0[b] = qv0[b];
                A1[b] = qv1[b];
                B0[b] = o ? qv0[b] : cv0[b];
                B1[b] = o ? qv1[b] : cv1[b];
            }
        }
        #pragma unroll
        for (int sub = 0; sub < 2; ++sub) {
            const float* ey0 = eyv[p][sub];
            float ey1[7];   // embed(rel1m + tm) = sign-derived
            ey1[0] = 1.0f;
            ey1[1] = ym * ey0[1]; ey1[2] = ym * ey0[2];
            ey1[3] = ey0[3];      ey1[4] = ey0[4];
            ey1[5] = ym * ey0[5]; ey1[6] = ym * ey0[6];

            float v00 = 0.0f, v01 = 0.0f, v10 = 0.0f, v11 = 0.0f;
            #pragma unroll
            for (int b = 0; b < 7; ++b) {
                v00 = fmaf(A0[b], ey0[b], v00);
                v10 = fmaf(A1[b], ey0[b], v10);
                v01 = fmaf(B0[b], ey1[b], v01);
                v11 = fmaf(B1[b], ey1[b], v11);
            }
            const float* w = wts[p][sub];
            float r = fmaf(v00, w[0], fmaf(v01, w[1], fmaf(v10, w[2], v11 * w[3])));
            if (p == 0) { if (sub == 0) acc0 = r; else acc1 = r; }
            else        { if (sub == 0) acc2 = r; else acc3 = r; }
        }
    }

    // ---- stores: two aligned float2 per thread ----
    const int i_out = fx ? (255 - i_e) : i_e;
    float* __restrict__ ob = out + (((size_t)n * 3 + k) * OHW + i_out) * OHW;
    const int jA = o ? 0   : (4 * jg - 2);
    const int jB = o ? 254 : (4 * jg);
    if (!fy) {
        *(float2*)&ob[jA] = make_float2(acc0, acc1);
        *(float2*)&ob[jB] = make_float2(acc2, acc3);
    } else {
        *(float2*)&ob[254 - jA] = make_float2(acc1, acc0);
        *(float2*)&ob[254 - jB] = make_float2(acc3, acc2);
    }
}

extern "C" void kernel_launch(void* const* d_in, const int* in_sizes, int n_in,
                              void* d_out, int out_size, void* d_ws, size_t ws_size,
                              hipStream_t stream) {
    const float* feat  = (const float*)d_in[0];
    const int*   flip1 = (const int*)d_in[3];
    const int*   flip3 = (const int*)d_in[4];
    float*       out   = (float*)d_out;

    dim3 grid(768);     // XCD-bijective decode in-kernel
    dim3 block(256);
    hipLaunchKernelGGL(ope_render_kernel, grid, block, 0, stream,
                       feat, flip1, flip3, out);
}

// Round 8
// 10.837 us; speedup vs baseline: 1.6003x; 1.6003x over previous
//
#include <hip/hip_runtime.h>
#include <math.h>

// feat: (N=4, C3=147, H=64, W=64) fp32 ; out: (4, 3, 256, 256) fp32
// Exact structure (proved in fp32, incl. the 1e-6 shift and clipping; verified
// by R5/R6/R7 all passing with identical absmax):
//  - interior j-group q (lane jg=q>=1): iw-minus = q-1, iw-plus = q for ALL
//    4 j's of the group; lane 0 (merged {0,1,254,255}): pair0 -> col 0 both,
//    pair1 -> col 63 both.  Same structure on the i axis per block.
//  - rel_plus = rel_minus - 2 (interior) or rel_minus (boundary) exactly ->
//    embed(rel-2) = sign-flip of embed(rel) on components {1,2,5,6}.
// This version: NO LDS, NO barrier. Each thread direct-loads its own column's
// 49ch x 2rows (perfectly coalesced per wave: lane=col), streams them into the
// ex-contraction, and gets the neighbor column's colvec via one 14-register
// intra-wave shuffle. Waves are fully independent -> no barrier amplification
// of HBM latency.

#define FH 64
#define FW 64
#define FHW 4096          // FH*FW
#define NC3 147
#define OHW 256

__device__ __forceinline__ void embed7(float r, float e[7]) {
    const float F1  = 1.5707963705062866f;  // float32(0.5*pi)
    const float SQ2 = 1.4142135381698608f;  // float32(sqrt(2))
    float a = r * F1;
    float s1 = __sinf(a), c1 = __cosf(a);
    float s2 = 2.0f * s1 * c1, c2 = c1 * c1 - s1 * s1;
    float s3 = s2 * c1 + c2 * s1, c3 = c2 * c1 - s2 * s1;
    e[0] = 1.0f;
    e[1] = SQ2 * c1; e[2] = SQ2 * s1;
    e[3] = SQ2 * c2; e[4] = SQ2 * s2;
    e[5] = SQ2 * c3; e[6] = SQ2 * s3;
}

// block = (k, ib, n); wave = i-member m; lane = j-group jg.
__global__ __launch_bounds__(256, 3) void ope_render_kernel(
    const float* __restrict__ feat,
    const int* __restrict__ pflip1,
    const int* __restrict__ pflip3,
    float* __restrict__ out)
{
    const int tid = threadIdx.x;
    const int k   = blockIdx.x;   // 0..2
    const int ib  = blockIdx.y;   // 0..63 (ib==0 merged {0,1,254,255})
    const int n   = blockIdx.z;   // 0..3
    const int flip1 = pflip1[0];
    const int flip3 = pflip3[0];

    const bool boundary = (ib == 0);
    const int rA = boundary ? 0  : (ib - 1);
    const int rB = boundary ? 63 : ib;

    const int m  = tid >> 6;      // wave id = i-member
    const int jg = tid & 63;      // lane = j-group
    const bool fx = (flip1 == 2) || (flip1 == 4);
    const bool fy = (flip1 == 1) || (flip1 == 4);
    const bool o  = (jg == 0);
    const float sgx = (flip3 == 2 || flip3 == 4) ? -1.0f : 1.0f;
    const float sgy = (flip3 == 1 || flip3 == 4) ? -1.0f : 1.0f;

    // x-axis: static rows; both corners' rel from one value
    const int i_e = boundary ? ((m < 2) ? m : 252 + m) : (4 * ib - 2 + m);
    const float cx = -1.0f + (2.0f * (float)i_e + 1.0f) * (1.0f / 256.0f);
    const int row0 = boundary ? ((m >> 1) ? rB : rA) : rA;   // minus-corner row
    const float qh0 = -1.0f + (2.0f * (float)row0 + 1.0f) * (1.0f / 64.0f);
    const float rel0_0 = (cx - qh0) * 64.0f;                  // exact
    const float rel0_1 = boundary ? rel0_0 : (rel0_0 - 2.0f); // exact

    float ex0[7], ex1[7];
    embed7(sgx * rel0_0, ex0);
    {   // embed(r -/+ 2) = sign-flip on {1,2,5,6}; boundary: identical
        const float xm = boundary ? 1.0f : -1.0f;
        ex1[0] = 1.0f;
        ex1[1] = xm * ex0[1]; ex1[2] = xm * ex0[2];
        ex1[3] = ex0[3];      ex1[4] = ex0[4];
        ex1[5] = xm * ex0[5]; ex1[6] = xm * ex0[6];
    }

    // ---- direct-global streamed contraction (no LDS, no barrier) ----
    // lane l reads col l -> each load is one coalesced 256B request per wave.
    const float* __restrict__ b0 =
        feat + (((size_t)n * NC3 + k * 49) * FH + row0) * FW + jg;
    float cv0[7], cv1[7];
    #pragma unroll
    for (int b = 0; b < 7; ++b) { cv0[b] = 0.0f; cv1[b] = 0.0f; }
    if (!boundary) {
        const float* __restrict__ b1 = b0 + (rB - rA) * FW;   // row rB, same ch
        #pragma unroll
        for (int c = 0; c < 49; ++c) {
            cv0[c % 7] = fmaf(ex0[c / 7], b0[c * FHW], cv0[c % 7]);
            cv1[c % 7] = fmaf(ex1[c / 7], b1[c * FHW], cv1[c % 7]);
        }
    } else {
        #pragma unroll
        for (int c = 0; c < 49; ++c)
            cv0[c % 7] = fmaf(ex0[c / 7], b0[c * FHW], cv0[c % 7]);
        #pragma unroll
        for (int b = 0; b < 7; ++b) cv1[b] = cv0[b];   // same row, ex1==ex0
    }

    // ---- neighbor column via intra-wave shuffle (lane jg-1; lane0 <- 63) ----
    const int srcl = (jg + 63) & 63;
    float qv0[7], qv1[7];
    #pragma unroll
    for (int b = 0; b < 7; ++b) {
        qv0[b] = __shfl(cv0[b], srcl, 64);
        qv1[b] = __shfl(cv1[b], srcl, 64);
    }

    // ---- per-pair inline y-math + dots (minimal live ranges, as R5) ----
    const float tm = o ? 0.0f : -2.0f;   // rel1_plus = rel1_minus + tm
    const float ym = o ? 1.0f : -1.0f;   // ey1 sign multiplier
    float acc0, acc1, acc2, acc3;
    #pragma unroll
    for (int p = 0; p < 2; ++p) {
        const int jb = o ? (p ? 254 : 0) : (4 * jg - 2 + 2 * p);
        const int cm = o ? (p ? 63 : 0) : (jg - 1);      // minus-corner col
        const float qwm = -1.0f + (2.0f * (float)cm + 1.0f) * (1.0f / 64.0f);

        // minus-corner colvec A, plus-corner colvec B (per dx):
        // p0: A = o?cv:qv, B = cv ;  p1: A = qv, B = o?qv:cv   (verified)
        float A0[7], A1[7], B0[7], B1[7];
        #pragma unroll
        for (int b = 0; b < 7; ++b) {
            if (p == 0) {
                A0[b] = o ? cv0[b] : qv0[b];
                A1[b] = o ? cv1[b] : qv1[b];
                B0[b] = cv0[b];
                B1[b] = cv1[b];
            } else {
                A0[b] = qv0[b];
                A1[b] = qv1[b];
                B0[b] = o ? qv0[b] : cv0[b];
                B1[b] = o ? qv1[b] : cv1[b];
            }
        }
        #pragma unroll
        for (int sub = 0; sub < 2; ++sub) {
            const int j_e = jb + sub;
            const float cy = -1.0f + (2.0f * (float)j_e + 1.0f) * (1.0f / 256.0f);
            const float rel1m = (cy - qwm) * 64.0f;      // exact
            const float rel1p = rel1m + tm;              // exact

            float a00 = fabsf(rel0_0 * rel1m) + 1e-9f;
            float a01 = fabsf(rel0_0 * rel1p) + 1e-9f;
            float a10 = fabsf(rel0_1 * rel1m) + 1e-9f;
            float a11 = fabsf(rel0_1 * rel1p) + 1e-9f;
            float tot = ((a00 + a01) + a10) + a11;
            float rinv = __builtin_amdgcn_rcpf(tot);
            const float w00 = a11 * rinv, w01 = a10 * rinv;
            const float w10 = a01 * rinv, w11 = a00 * rinv;

            float ey0[7], ey1[7];
            embed7(sgy * rel1m, ey0);
            ey1[0] = 1.0f;
            ey1[1] = ym * ey0[1]; ey1[2] = ym * ey0[2];
            ey1[3] = ey0[3];      ey1[4] = ey0[4];
            ey1[5] = ym * ey0[5]; ey1[6] = ym * ey0[6];

            float v00 = 0.0f, v01 = 0.0f, v10 = 0.0f, v11 = 0.0f;
            #pragma unroll
            for (int b = 0; b < 7; ++b) {
                v00 = fmaf(A0[b], ey0[b], v00);
                v10 = fmaf(A1[b], ey0[b], v10);
                v01 = fmaf(B0[b], ey1[b], v01);
                v11 = fmaf(B1[b], ey1[b], v11);
            }
            float r = fmaf(v00, w00, fmaf(v01, w01, fmaf(v10, w10, v11 * w11)));
            if (p == 0) { if (sub == 0) acc0 = r; else acc1 = r; }
            else        { if (sub == 0) acc2 = r; else acc3 = r; }
        }
    }

    // ---- stores: two aligned float2 per thread ----
    const int i_out = fx ? (255 - i_e) : i_e;
    float* __restrict__ ob = out + (((size_t)n * 3 + k) * OHW + i_out) * OHW;
    const int jA = o ? 0   : (4 * jg - 2);
    const int jB = o ? 254 : (4 * jg);
    if (!fy) {
        *(float2*)&ob[jA] = make_float2(acc0, acc1);
        *(float2*)&ob[jB] = make_float2(acc2, acc3);
    } else {
        *(float2*)&ob[254 - jA] = make_float2(acc1, acc0);
        *(float2*)&ob[254 - jB] = make_float2(acc3, acc2);
    }
}

extern "C" void kernel_launch(void* const* d_in, const int* in_sizes, int n_in,
                              void* d_out, int out_size, void* d_ws, size_t ws_size,
                              hipStream_t stream) {
    const float* feat  = (const float*)d_in[0];
    const int*   flip1 = (const int*)d_in[3];
    const int*   flip3 = (const int*)d_in[4];
    float*       out   = (float*)d_out;

    dim3 grid(3, 64, 4);   // (k, i-group, n) — R4-R6 arrangement (best known)
    dim3 block(256);
    hipLaunchKernelGGL(ope_render_kernel, grid, block, 0, stream,
                       feat, flip1, flip3, out);
}